// Round 13
// baseline (158.459 us; speedup 1.0000x reference)
//
#include <hip/hip_runtime.h>
#include <stdint.h>

#define B_ 16
#define S_ 128
#define H_ 768
#define K_ 4
#define L_ 2
#define T_ (B_*S_)   // 2048

typedef __attribute__((ext_vector_type(4))) float f32x4;
typedef __attribute__((ext_vector_type(8))) short s16x8;
typedef __bf16 bf16x8 __attribute__((ext_vector_type(8)));
typedef unsigned short u16;

// ---------- bf16 helpers ----------
__device__ inline u16 f2bf(float f) {
    union { float f; uint32_t u; } v; v.f = f;
    uint32_t u = v.u;
    return (u16)((u + 0x7fffu + ((u >> 16) & 1u)) >> 16);
}

__device__ inline ushort4 f2bf4(float4 v) {
    ushort4 r; r.x = f2bf(v.x); r.y = f2bf(v.y); r.z = f2bf(v.z); r.w = f2bf(v.w);
    return r;
}

// ---------- MFMA wrapper: tolerant to either builtin signature ----------
template <typename T>
__device__ inline auto mfma16_impl(T a, T b, f32x4 c, int)
    -> decltype(__builtin_amdgcn_mfma_f32_16x16x32_bf16(a, b, c, 0, 0, 0)) {
    return __builtin_amdgcn_mfma_f32_16x16x32_bf16(a, b, c, 0, 0, 0);
}
template <typename T>
__device__ inline f32x4 mfma16_impl(T a, T b, f32x4 c, long) {
    return __builtin_amdgcn_mfma_f32_16x16x32_bf16(
        __builtin_bit_cast(bf16x8, a), __builtin_bit_cast(bf16x8, b), c, 0, 0, 0);
}
__device__ inline f32x4 mfma16(s16x8 a, s16x8 b, f32x4 c) {
    return mfma16_impl(a, b, c, 0);
}

// ---------- async global->LDS, 16B/lane ----------
__device__ inline void gload_lds16(const void* g, void* l) {
    __builtin_amdgcn_global_load_lds(
        (__attribute__((address_space(1))) void*)(g),
        (__attribute__((address_space(3))) void*)(l), 16, 0, 0);
}

// ---- 512-thread (8-wave) stage of a 128x64-bf16 tile (XOR-swizzled, proven) ----
__device__ inline void stage128(const char* gRow0, int rowStrideBytes, char* ldsBase, int tid) {
    const int lane = tid & 63;
    const int w = tid >> 6;           // 0..7
    const int lr = lane >> 3;
    #pragma unroll
    for (int j = 0; j < 2; ++j) {
        const int seg = w * 2 + j;          // 0..15
        const int row = seg * 8 + lr;       // 0..127
        const int sb = ((lane & 7) << 4) ^ ((row & 7) << 4);
        gload_lds16(gRow0 + (size_t)row * rowStrideBytes + sb,
                    ldsBase + seg * 1024);
    }
}

// ---- 256-thread (4-wave) stage of a 128x64-bf16 tile (gemm2) ----
__device__ inline void stage_tile(const char* gbase, int rowStrideBytes, u16* lds, int tid) {
    const int lane = tid & 63;
    const int w = tid >> 6;
    const int lr = lane >> 3;
    const int cb = (lane & 7) << 4;
    #pragma unroll
    for (int j = 0; j < 4; ++j) {
        const int seg = j * 4 + w;
        const int row = seg * 8 + lr;
        const int sb = cb ^ ((row & 7) << 4);
        gload_lds16(gbase + (size_t)row * rowStrideBytes + sb, lds + seg * 512);
    }
}

// ---- 256-thread stage of a 64x64-bf16 tile (gemm2) ----
__device__ inline void stage64(const char* gbase, int rowStrideBytes, char* lds, int tid) {
    const int lane = tid & 63;
    const int w = tid >> 6;
    const int lr = lane >> 3;
    const int cb = (lane & 7) << 4;
    #pragma unroll
    for (int j = 0; j < 2; ++j) {
        const int seg = j * 4 + w;
        const int row = seg * 8 + lr;
        const int sb = cb ^ ((row & 7) << 4);
        gload_lds16(gbase + (size_t)row * rowStrideBytes + sb, lds + seg * 1024);
    }
}

// Swizzled ds_read_b128 of an MFMA fragment (128-B rows, any contiguous row count)
__device__ inline s16x8 read_frag(const u16* lds, int row, int colByte) {
    const int bir = colByte ^ ((row & 7) << 4);
    return *(const s16x8*)((const char*)lds + row * 128 + bir);
}

// ---------- prep kernels (proven) ----------
__global__ void prep_weights(const float* __restrict__ Wg_in, const float* __restrict__ Wg_out,
                             const float* __restrict__ W_in,  const float* __restrict__ W_out,
                             const float* __restrict__ W_loop, const float* __restrict__ sent,
                             u16* __restrict__ Wg_all, u16* __restrict__ W_all,
                             u16* __restrict__ Wl, u16* __restrict__ X0) {
    const int i4 = blockIdx.x * blockDim.x + threadIdx.x;   // float4 index
    const int NW4 = L_ * K_ * H_ * H_ / 4;                  // 1,179,648
    const int KHH4 = K_ * H_ * H_ / 4;
    if (i4 < NW4) {
        const int l = i4 / KHH4;
        const int rem = i4 - l * KHH4;
        const int d0 = (l * 2) * KHH4 + rem;
        const int d1 = d0 + KHH4;
        ((ushort4*)Wg_all)[d0] = f2bf4(((const float4*)Wg_in)[i4]);
        ((ushort4*)Wg_all)[d1] = f2bf4(((const float4*)Wg_out)[i4]);
        ((ushort4*)W_all)[d0]  = f2bf4(((const float4*)W_in)[i4]);
        ((ushort4*)W_all)[d1]  = f2bf4(((const float4*)W_out)[i4]);
    }
    if (i4 < L_ * H_ * H_ / 4)  ((ushort4*)Wl)[i4] = f2bf4(((const float4*)W_loop)[i4]);
    if (i4 < T_ * H_ / 4)       ((ushort4*)X0)[i4] = f2bf4(((const float4*)sent)[i4]);
}

// adjA[p][b][t][s]: p=dir*4+k; dir 0 (in): adj[b,k,s,t] (transposed), dir 1 (out): adj[b,k,t,s]
__global__ void prep_adj(const float* __restrict__ adj, u16* __restrict__ adjA) {
    const int idx = blockIdx.x * blockDim.x + threadIdx.x;
    const int s = idx & 127;
    const int t = (idx >> 7) & 127;
    const int b = (idx >> 14) & 15;
    const int p = idx >> 18;
    const int dir = p >> 2, k = p & 3;
    const float v = dir ? adj[(((size_t)b * K_ + k) * S_ + t) * S_ + s]
                        : adj[(((size_t)b * K_ + k) * S_ + s) * S_ + t];
    adjA[idx] = f2bf(v);
}

// ---------- GEMM 1: persistent + triple-buffer + COUNTED vmcnt (never drain) ----------
// 256 blocks x 3 tasks (task = 128tok x 128h rel+gate, 12 K-tiles of BK=64).
// LDS = 3 x 48KB; ONE raw s_barrier per K-tile; steady-state wait is vmcnt(6)
// (allows the just-issued stage(vt+2) to stay in flight ACROSS the barrier).
// Epilogue iters wait vmcnt(14) (8 stores + 6 stage loads are newest).
// p = bid&7 -> problem pinned to XCD (weights L2-resident).
__global__ __launch_bounds__(512, 1)
void gemm1_kernel(const u16* __restrict__ Xb,
                  const u16* __restrict__ Wg_all, const u16* __restrict__ W_all,
                  const float* __restrict__ bg_in, const float* __restrict__ bg_out,
                  const float* __restrict__ b_in,  const float* __restrict__ b_out,
                  int layer, u16* __restrict__ Rel2) {
    __shared__ __align__(16) char smem[147456];   // 3 x (A 16K + Br 16K + Bg 16K)

    const int tid = threadIdx.x;
    const int lane = tid & 63;
    const int w = tid >> 6;
    const int wm = w >> 2;                 // 0..1 (64-tok half)
    const int wn = w & 3;                  // 0..3 (32-h slice)
    const int l15 = lane & 15;
    const int hi16 = (lane >> 4) << 4;

    const int bid = blockIdx.x;
    const int p = bid & 7;                 // problem == XCD
    const int g = bid >> 3;                // 0..31 within problem
    const int dir = p >> 2, kk = p & 3;
    const size_t woff = ((size_t)(layer * 2 + dir) * K_ + kk) * (size_t)(H_ * H_);
    const char* Wr0 = (const char*)(W_all + woff);
    const char* Wg0 = (const char*)(Wg_all + woff);

    const float* bgp = (dir ? bg_out : bg_in) + ((size_t)layer * K_ + kk) * H_;
    const float* brp = (dir ? b_out  : b_in ) + ((size_t)layer * K_ + kk) * H_;

    // stage task t2 (0..2), K-tile k2 (0..11) into buffer c2 (0..2)
    auto STAGE_TK = [&](int t2, int k2, int c2) {
        const int tsk = g * 3 + t2;        // 0..95
        const int y = tsk >> 4;            // 0..5
        const int m = tsk & 15;            // 0..15
        const size_t kb = (size_t)k2 * 128;
        char* base = smem + c2 * 49152;
        stage128((const char*)Xb + (size_t)(m * 128) * (H_ * 2) + kb, H_ * 2, base, tid);
        stage128(Wr0 + (size_t)(y * 128) * (H_ * 2) + kb, H_ * 2, base + 16384, tid);
        stage128(Wg0 + (size_t)(y * 128) * (H_ * 2) + kb, H_ * 2, base + 32768, tid);
    };

    const f32x4 zf = {0.f, 0.f, 0.f, 0.f};
    f32x4 accr[4][2], accg[4][2];
    #pragma unroll
    for (int i = 0; i < 4; ++i)
        #pragma unroll
        for (int j = 0; j < 2; ++j) { accr[i][j] = zf; accg[i][j] = zf; }

    // prologue: stage vt=0 (buf0) and vt=1 (buf1); wait only for vt=0.
    STAGE_TK(0, 0, 0);
    STAGE_TK(0, 1, 1);
    asm volatile("s_waitcnt vmcnt(6)" ::: "memory");
    __builtin_amdgcn_s_barrier();
    __builtin_amdgcn_sched_barrier(0);

    int c = 0;                             // rotating buffer index = vt % 3
    #pragma unroll 1
    for (int ti = 0; ti < 3; ++ti) {
        #pragma unroll 1
        for (int kt = 0; kt < 12; ++kt) {
            const int vt = ti * 12 + kt;
            // issue stage(vt+2) FIRST (stays newest-but-one in the vmcnt FIFO)
            if (vt + 2 < 36) {
                int t2 = ti, k2 = kt + 2;
                if (k2 >= 12) { t2 = ti + 1; k2 -= 12; }
                int c2 = c + 2; if (c2 >= 3) c2 -= 3;
                STAGE_TK(t2, k2, c2);
            }
            const u16* lA  = (const u16*)(smem + c * 49152);
            const u16* lBr = (const u16*)(smem + c * 49152 + 16384);
            const u16* lBg = (const u16*)(smem + c * 49152 + 32768);
            #pragma unroll
            for (int kq = 0; kq < 2; ++kq) {
                const int ck = kq * 64 + hi16;
                s16x8 a[4], br[2], bg[2];
                #pragma unroll
                for (int i = 0; i < 4; ++i)
                    a[i] = read_frag(lA, wm * 64 + i * 16 + l15, ck);
                #pragma unroll
                for (int j = 0; j < 2; ++j) {
                    br[j] = read_frag(lBr, wn * 32 + j * 16 + l15, ck);
                    bg[j] = read_frag(lBg, wn * 32 + j * 16 + l15, ck);
                }
                __builtin_amdgcn_s_setprio(1);
                #pragma unroll
                for (int i = 0; i < 4; ++i) {
                    #pragma unroll
                    for (int j = 0; j < 2; ++j) {
                        accr[i][j] = mfma16(a[i], br[j], accr[i][j]);
                        accg[i][j] = mfma16(a[i], bg[j], accg[i][j]);
                    }
                }
                __builtin_amdgcn_s_setprio(0);
            }
            // wave-local epilogue at task end (8 global stores/thread)
            if (kt == 11) {
                const int tsk = g * 3 + ti;
                const int y = tsk >> 4;
                const int m = tsk & 15;
                #pragma unroll
                for (int j = 0; j < 2; ++j) {
                    const int h = y * 128 + wn * 32 + j * 16 + l15;
                    const float bgv = bgp[h];
                    const float brv = brp[h];
                    #pragma unroll
                    for (int i = 0; i < 4; ++i) {
                        const int tl = wm * 64 + i * 16 + ((lane >> 4) << 2);
                        u16 tmp[4];
                        #pragma unroll
                        for (int rr = 0; rr < 4; ++rr) {
                            const float gv = accg[i][j][rr] + bgv;
                            const float vv = accr[i][j][rr] + brv;
                            tmp[rr] = f2bf(0.5f * vv / (1.f + __expf(-gv)));
                        }
                        ushort4 pk; pk.x = tmp[0]; pk.y = tmp[1]; pk.z = tmp[2]; pk.w = tmp[3];
                        *(ushort4*)(Rel2 + (((size_t)p * B_ + m) * H_ + h) * S_ + tl) = pk;
                        accr[i][j] = zf; accg[i][j] = zf;
                    }
                }
            }
            // counted wait: ensure stage(vt+1) landed; stage(vt+2) stays in flight.
            if (vt < 35) {
                if (kt == 11)      asm volatile("s_waitcnt vmcnt(14)" ::: "memory");
                else if (vt == 34) asm volatile("s_waitcnt vmcnt(0)"  ::: "memory");
                else               asm volatile("s_waitcnt vmcnt(6)"  ::: "memory");
                __builtin_amdgcn_sched_barrier(0);
                __builtin_amdgcn_s_barrier();
                __builtin_amdgcn_sched_barrier(0);
            }
            ++c; if (c == 3) c = 0;
        }
    }
}

// ---------- GEMM 2: self-loop GEMM + adjacency contraction + ReLU (proven) ----------
// 28 iterations: q<12 = loop GEMM (X . Wl^T, K=768), q>=12 = adjacency (8p x 2).
// grid (12 h-tiles of 64, 16 batches), block 256 (4 waves 2x2).
__global__ __launch_bounds__(256, 2)
void gemm2_kernel(const u16* __restrict__ adjA, const u16* __restrict__ Rel2,
                  const u16* __restrict__ Xc, const u16* __restrict__ Wlb,
                  int layer,
                  u16* __restrict__ Xn, float* __restrict__ Out, int lastLayer) {
    __shared__ __align__(16) char smem2[49152];   // 2 x (A 16K + B 8K)

    const int tid = threadIdx.x;
    const int lane = tid & 63;
    const int w = tid >> 6;
    const int wm = w >> 1, wn = w & 1;
    const int l15 = lane & 15;
    const int hi16 = (lane >> 4) << 4;
    const int h0 = blockIdx.x * 64;
    const int b = blockIdx.y;

    const char* gX  = (const char*)Xc + ((size_t)b * S_) * (H_ * 2);
    const char* gWl = (const char*)(Wlb + (size_t)layer * H_ * H_) + (size_t)h0 * (H_ * 2);

    auto STAGE = [&](int q, int c) {
        char* base = smem2 + c * 24576;
        if (q < 12) {
            stage_tile(gX + (size_t)q * 128, H_ * 2, (u16*)base, tid);
            stage64(gWl + (size_t)q * 128, H_ * 2, base + 16384, tid);
        } else {
            const int qa = q - 12;
            const int p = qa >> 1, sc = qa & 1;
            const char* Ab = (const char*)adjA + ((size_t)p * B_ + b) * (S_ * S_ * 2) + sc * 128;
            const char* Bb = (const char*)Rel2 + (((size_t)p * B_ + b) * H_ + h0) * (S_ * 2) + sc * 128;
            stage_tile(Ab, S_ * 2, (u16*)base, tid);
            stage64(Bb, S_ * 2, base + 16384, tid);
        }
    };

    const f32x4 zf = {0.f, 0.f, 0.f, 0.f};
    f32x4 acc[4][2];
    #pragma unroll
    for (int i = 0; i < 4; ++i)
        #pragma unroll
        for (int j = 0; j < 2; ++j) acc[i][j] = zf;

    STAGE(0, 0);
    __syncthreads();

    for (int q = 0; q < 28; ++q) {
        const int c = q & 1;
        if (q < 27) STAGE(q + 1, c ^ 1);
        const u16* lA = (const u16*)(smem2 + c * 24576);
        const u16* lB = (const u16*)(smem2 + c * 24576 + 16384);
        #pragma unroll
        for (int kq = 0; kq < 2; ++kq) {
            const int ck = kq * 64 + hi16;
            s16x8 a[4], bb[2];
            #pragma unroll
            for (int i = 0; i < 4; ++i)
                a[i] = read_frag(lA, wm * 64 + i * 16 + l15, ck);
            #pragma unroll
            for (int j = 0; j < 2; ++j)
                bb[j] = read_frag(lB, wn * 32 + j * 16 + l15, ck);
            #pragma unroll
            for (int i = 0; i < 4; ++i)
                #pragma unroll
                for (int j = 0; j < 2; ++j)
                    acc[i][j] = mfma16(a[i], bb[j], acc[i][j]);
        }
        __syncthreads();
    }

    #pragma unroll
    for (int i = 0; i < 4; ++i) {
        const int tl = wm * 64 + i * 16 + ((lane >> 4) << 2);
        #pragma unroll
        for (int j = 0; j < 2; ++j) {
            const int h = h0 + wn * 32 + j * 16 + l15;
            #pragma unroll
            for (int rr = 0; rr < 4; ++rr) {
                const size_t t = (size_t)b * S_ + tl + rr;
                float v = fmaxf(acc[i][j][rr], 0.f);
                if (lastLayer) Out[t * H_ + h] = v;
                else           Xn[t * H_ + h] = f2bf(v);
            }
        }
    }
}

// ---------- launch ----------
extern "C" void kernel_launch(void* const* d_in, const int* in_sizes, int n_in,
                              void* d_out, int out_size, void* d_ws, size_t ws_size,
                              hipStream_t stream) {
    const float* sent   = (const float*)d_in[0];
    const float* adj    = (const float*)d_in[1];
    const float* W_in   = (const float*)d_in[2];
    const float* b_in   = (const float*)d_in[3];
    const float* W_out  = (const float*)d_in[4];
    const float* b_out  = (const float*)d_in[5];
    const float* Wg_in  = (const float*)d_in[6];
    const float* bg_in  = (const float*)d_in[7];
    const float* Wg_out = (const float*)d_in[8];
    const float* bg_out = (const float*)d_in[9];
    const float* W_loop = (const float*)d_in[10];

    char* ws = (char*)d_ws;
    u16* Wg_all = (u16*)(ws);                  // 18,874,368 B
    u16* W_all  = (u16*)(ws + 18874368);       // 18,874,368 B
    u16* Wlb    = (u16*)(ws + 37748736);       //  2,359,296 B
    u16* adjA   = (u16*)(ws + 40108032);       //  4,194,304 B
    u16* X0     = (u16*)(ws + 44302336);       //  3,145,728 B
    u16* X1     = (u16*)(ws + 47448064);       //  3,145,728 B
    u16* Rel2   = (u16*)(ws + 50593792);       // 25,165,824 B  (end 75,759,616)

    prep_weights<<<4608, 256, 0, stream>>>(Wg_in, Wg_out, W_in, W_out, W_loop, sent,
                                           Wg_all, W_all, Wlb, X0);
    prep_adj<<<8192, 256, 0, stream>>>(adj, adjA);

    u16* Xc = X0;
    u16* Xn = X1;
    for (int l = 0; l < L_; ++l) {
        gemm1_kernel<<<256, 512, 0, stream>>>(Xc, Wg_all, W_all,
                                              bg_in, bg_out, b_in, b_out,
                                              l, Rel2);
        gemm2_kernel<<<dim3(12, 16), 256, 0, stream>>>(adjA, Rel2, Xc, Wlb, l,
                                                       Xn, (float*)d_out, l == L_ - 1);
        u16* t = Xc; Xc = Xn; Xn = t;
    }
}

// Round 14
// 153.676 us; speedup vs baseline: 1.0311x; 1.0311x over previous
//
#include <hip/hip_runtime.h>
#include <stdint.h>

#define B_ 16
#define S_ 128
#define H_ 768
#define K_ 4
#define L_ 2
#define T_ (B_*S_)   // 2048

typedef __attribute__((ext_vector_type(4))) float f32x4;
typedef __attribute__((ext_vector_type(8))) short s16x8;
typedef __bf16 bf16x8 __attribute__((ext_vector_type(8)));
typedef unsigned short u16;

// ---------- bf16 helpers ----------
__device__ inline u16 f2bf(float f) {
    union { float f; uint32_t u; } v; v.f = f;
    uint32_t u = v.u;
    return (u16)((u + 0x7fffu + ((u >> 16) & 1u)) >> 16);
}

__device__ inline ushort4 f2bf4(float4 v) {
    ushort4 r; r.x = f2bf(v.x); r.y = f2bf(v.y); r.z = f2bf(v.z); r.w = f2bf(v.w);
    return r;
}

// ---------- MFMA wrapper: tolerant to either builtin signature ----------
template <typename T>
__device__ inline auto mfma16_impl(T a, T b, f32x4 c, int)
    -> decltype(__builtin_amdgcn_mfma_f32_16x16x32_bf16(a, b, c, 0, 0, 0)) {
    return __builtin_amdgcn_mfma_f32_16x16x32_bf16(a, b, c, 0, 0, 0);
}
template <typename T>
__device__ inline f32x4 mfma16_impl(T a, T b, f32x4 c, long) {
    return __builtin_amdgcn_mfma_f32_16x16x32_bf16(
        __builtin_bit_cast(bf16x8, a), __builtin_bit_cast(bf16x8, b), c, 0, 0, 0);
}
__device__ inline f32x4 mfma16(s16x8 a, s16x8 b, f32x4 c) {
    return mfma16_impl(a, b, c, 0);
}

// ---------- async global->LDS, 16B/lane ----------
__device__ inline void gload_lds16(const void* g, void* l) {
    __builtin_amdgcn_global_load_lds(
        (__attribute__((address_space(1))) void*)(g),
        (__attribute__((address_space(3))) void*)(l), 16, 0, 0);
}

// ---- 512-thread (8-wave) stage of a 128x64-bf16 tile (XOR-swizzled, proven) ----
__device__ inline void stage128(const char* gRow0, int rowStrideBytes, char* ldsBase, int tid) {
    const int lane = tid & 63;
    const int w = tid >> 6;           // 0..7
    const int lr = lane >> 3;
    #pragma unroll
    for (int j = 0; j < 2; ++j) {
        const int seg = w * 2 + j;          // 0..15
        const int row = seg * 8 + lr;       // 0..127
        const int sb = ((lane & 7) << 4) ^ ((row & 7) << 4);
        gload_lds16(gRow0 + (size_t)row * rowStrideBytes + sb,
                    ldsBase + seg * 1024);
    }
}

// ---- 256-thread (4-wave) stage of a 128x64-bf16 tile (gemm2) ----
__device__ inline void stage_tile(const char* gbase, int rowStrideBytes, u16* lds, int tid) {
    const int lane = tid & 63;
    const int w = tid >> 6;
    const int lr = lane >> 3;
    const int cb = (lane & 7) << 4;
    #pragma unroll
    for (int j = 0; j < 4; ++j) {
        const int seg = j * 4 + w;
        const int row = seg * 8 + lr;
        const int sb = cb ^ ((row & 7) << 4);
        gload_lds16(gbase + (size_t)row * rowStrideBytes + sb, lds + seg * 512);
    }
}

// ---- 256-thread stage of a 64x64-bf16 tile (gemm2) ----
__device__ inline void stage64(const char* gbase, int rowStrideBytes, char* lds, int tid) {
    const int lane = tid & 63;
    const int w = tid >> 6;
    const int lr = lane >> 3;
    const int cb = (lane & 7) << 4;
    #pragma unroll
    for (int j = 0; j < 2; ++j) {
        const int seg = j * 4 + w;
        const int row = seg * 8 + lr;
        const int sb = cb ^ ((row & 7) << 4);
        gload_lds16(gbase + (size_t)row * rowStrideBytes + sb, lds + seg * 1024);
    }
}

// Swizzled ds_read_b128 of an MFMA fragment (128-B rows, any contiguous row count)
__device__ inline s16x8 read_frag(const u16* lds, int row, int colByte) {
    const int bir = colByte ^ ((row & 7) << 4);
    return *(const s16x8*)((const char*)lds + row * 128 + bir);
}

// ---------- prep kernels (proven) ----------
__global__ void prep_weights(const float* __restrict__ Wg_in, const float* __restrict__ Wg_out,
                             const float* __restrict__ W_in,  const float* __restrict__ W_out,
                             const float* __restrict__ W_loop, const float* __restrict__ sent,
                             u16* __restrict__ Wg_all, u16* __restrict__ W_all,
                             u16* __restrict__ Wl, u16* __restrict__ X0) {
    const int i4 = blockIdx.x * blockDim.x + threadIdx.x;   // float4 index
    const int NW4 = L_ * K_ * H_ * H_ / 4;                  // 1,179,648
    const int KHH4 = K_ * H_ * H_ / 4;
    if (i4 < NW4) {
        const int l = i4 / KHH4;
        const int rem = i4 - l * KHH4;
        const int d0 = (l * 2) * KHH4 + rem;
        const int d1 = d0 + KHH4;
        ((ushort4*)Wg_all)[d0] = f2bf4(((const float4*)Wg_in)[i4]);
        ((ushort4*)Wg_all)[d1] = f2bf4(((const float4*)Wg_out)[i4]);
        ((ushort4*)W_all)[d0]  = f2bf4(((const float4*)W_in)[i4]);
        ((ushort4*)W_all)[d1]  = f2bf4(((const float4*)W_out)[i4]);
    }
    if (i4 < L_ * H_ * H_ / 4)  ((ushort4*)Wl)[i4] = f2bf4(((const float4*)W_loop)[i4]);
    if (i4 < T_ * H_ / 4)       ((ushort4*)X0)[i4] = f2bf4(((const float4*)sent)[i4]);
}

// adjA[p][b][t][s]: p=dir*4+k; dir 0 (in): adj[b,k,s,t] (transposed), dir 1 (out): adj[b,k,t,s]
__global__ void prep_adj(const float* __restrict__ adj, u16* __restrict__ adjA) {
    const int idx = blockIdx.x * blockDim.x + threadIdx.x;
    const int s = idx & 127;
    const int t = (idx >> 7) & 127;
    const int b = (idx >> 14) & 15;
    const int p = idx >> 18;
    const int dir = p >> 2, k = p & 3;
    const float v = dir ? adj[(((size_t)b * K_ + k) * S_ + t) * S_ + s]
                        : adj[(((size_t)b * K_ + k) * S_ + s) * S_ + t];
    adjA[idx] = f2bf(v);
}

// ---------- GEMM 1: persistent, perfectly balanced (256 blocks x 3 tasks) ----------
// Task = 128tok x 128h (rel+gate), BK=64, 12 K-tiles. Block = 512 threads, 8 waves
// (2m x 4n), per-wave 64tok x 32h rel+gate (acc 64 VGPR). LDS 2 x 48KB dbuf.
// p = bid&7 -> problem pinned to XCD (weights L2-resident); 3 tasks run back-to-back
// in ONE continuous 2-phase pipeline (36 virtual K-tiles, one prologue, zero tail).
// Epilogues are wave-local register dumps at task boundaries (no extra barriers).
// [BEST MEASURED: r12, 152.9 us total — restored verbatim]
__global__ __launch_bounds__(512, 2)
void gemm1_kernel(const u16* __restrict__ Xb,
                  const u16* __restrict__ Wg_all, const u16* __restrict__ W_all,
                  const float* __restrict__ bg_in, const float* __restrict__ bg_out,
                  const float* __restrict__ b_in,  const float* __restrict__ b_out,
                  int layer, u16* __restrict__ Rel2) {
    __shared__ __align__(16) char smem[98304];   // 2 x (A 16K + Br 16K + Bg 16K)

    const int tid = threadIdx.x;
    const int lane = tid & 63;
    const int w = tid >> 6;
    const int wm = w >> 2;                 // 0..1 (64-tok half)
    const int wn = w & 3;                  // 0..3 (32-h slice)
    const int l15 = lane & 15;
    const int hi16 = (lane >> 4) << 4;

    const int bid = blockIdx.x;
    const int p = bid & 7;                 // problem == XCD
    const int g = bid >> 3;                // 0..31 within problem
    const int dir = p >> 2, kk = p & 3;
    const size_t woff = ((size_t)(layer * 2 + dir) * K_ + kk) * (size_t)(H_ * H_);

    // 3 tasks: idx = g*3+i -> y = idx/16 (h-tile), m = idx%16 (batch)
    const char* gAt[3];
    const char* gBrt[3];
    const char* gBgt[3];
    int ys[3], ms[3];
    #pragma unroll
    for (int i = 0; i < 3; ++i) {
        const int task = g * 3 + i;
        const int y = task / 16, m = task % 16;
        ys[i] = y; ms[i] = m;
        gAt[i]  = (const char*)Xb + (size_t)(m * 128) * (H_ * 2);
        gBrt[i] = (const char*)(W_all + woff)  + (size_t)(y * 128) * (H_ * 2);
        gBgt[i] = (const char*)(Wg_all + woff) + (size_t)(y * 128) * (H_ * 2);
    }

    const float* bgp = (dir ? bg_out : bg_in) + ((size_t)layer * K_ + kk) * H_;
    const float* brp = (dir ? b_out  : b_in ) + ((size_t)layer * K_ + kk) * H_;

    auto STAGE = [&](int i, int kt, int c) {
        char* base = smem + c * 49152;
        stage128(gAt[i]  + (size_t)kt * 128, H_ * 2, base, tid);
        stage128(gBrt[i] + (size_t)kt * 128, H_ * 2, base + 16384, tid);
        stage128(gBgt[i] + (size_t)kt * 128, H_ * 2, base + 32768, tid);
    };

    const f32x4 zf = {0.f, 0.f, 0.f, 0.f};
    f32x4 accr[4][2], accg[4][2];
    #pragma unroll
    for (int i = 0; i < 4; ++i)
        #pragma unroll
        for (int j = 0; j < 2; ++j) { accr[i][j] = zf; accg[i][j] = zf; }

    STAGE(0, 0, 0);
    __syncthreads();

    #pragma unroll
    for (int ti = 0; ti < 3; ++ti) {
        for (int kt = 0; kt < 12; ++kt) {
            const int c = kt & 1;
            if (kt < 11)      STAGE(ti, kt + 1, c ^ 1);
            else if (ti < 2)  STAGE(ti + 1, 0, c ^ 1);
            const u16* lA  = (const u16*)(smem + c * 49152);
            const u16* lBr = (const u16*)(smem + c * 49152 + 16384);
            const u16* lBg = (const u16*)(smem + c * 49152 + 32768);
            #pragma unroll
            for (int kq = 0; kq < 2; ++kq) {
                const int ck = kq * 64 + hi16;
                s16x8 a[4], br[2], bg[2];
                #pragma unroll
                for (int i = 0; i < 4; ++i)
                    a[i] = read_frag(lA, wm * 64 + i * 16 + l15, ck);
                #pragma unroll
                for (int j = 0; j < 2; ++j) {
                    br[j] = read_frag(lBr, wn * 32 + j * 16 + l15, ck);
                    bg[j] = read_frag(lBg, wn * 32 + j * 16 + l15, ck);
                }
                #pragma unroll
                for (int i = 0; i < 4; ++i) {
                    #pragma unroll
                    for (int j = 0; j < 2; ++j) {
                        accr[i][j] = mfma16(a[i], br[j], accr[i][j]);
                        accg[i][j] = mfma16(a[i], bg[j], accg[i][j]);
                    }
                }
            }
            __syncthreads();
        }
        // ---- wave-local epilogue for task ti (no barrier; next task's tile 0
        // is already staged and drained by the kt=11 __syncthreads) ----
        {
            const int y = ys[ti], m = ms[ti];
            #pragma unroll
            for (int j = 0; j < 2; ++j) {
                const int h = y * 128 + wn * 32 + j * 16 + l15;
                const float bgv = bgp[h];
                const float brv = brp[h];
                #pragma unroll
                for (int i = 0; i < 4; ++i) {
                    const int tl = wm * 64 + i * 16 + ((lane >> 4) << 2);   // 0..127
                    u16 tmp[4];
                    #pragma unroll
                    for (int rr = 0; rr < 4; ++rr) {
                        const float gv = accg[i][j][rr] + bgv;
                        const float vv = accr[i][j][rr] + brv;
                        tmp[rr] = f2bf(0.5f * vv / (1.f + __expf(-gv)));
                    }
                    ushort4 pk; pk.x = tmp[0]; pk.y = tmp[1]; pk.z = tmp[2]; pk.w = tmp[3];
                    *(ushort4*)(Rel2 + (((size_t)p * B_ + m) * H_ + h) * S_ + tl) = pk;
                    accr[i][j] = zf; accg[i][j] = zf;
                }
            }
        }
    }
}

// ---------- GEMM 2: self-loop GEMM + adjacency contraction + ReLU (proven) ----------
// 28 iterations: q<12 = loop GEMM (X . Wl^T, K=768), q>=12 = adjacency (8p x 2).
// grid (12 h-tiles of 64, 16 batches), block 256 (4 waves 2x2).
__global__ __launch_bounds__(256, 2)
void gemm2_kernel(const u16* __restrict__ adjA, const u16* __restrict__ Rel2,
                  const u16* __restrict__ Xc, const u16* __restrict__ Wlb,
                  int layer,
                  u16* __restrict__ Xn, float* __restrict__ Out, int lastLayer) {
    __shared__ __align__(16) char smem2[49152];   // 2 x (A 16K + B 8K)

    const int tid = threadIdx.x;
    const int lane = tid & 63;
    const int w = tid >> 6;
    const int wm = w >> 1, wn = w & 1;
    const int l15 = lane & 15;
    const int hi16 = (lane >> 4) << 4;
    const int h0 = blockIdx.x * 64;
    const int b = blockIdx.y;

    const char* gX  = (const char*)Xc + ((size_t)b * S_) * (H_ * 2);
    const char* gWl = (const char*)(Wlb + (size_t)layer * H_ * H_) + (size_t)h0 * (H_ * 2);

    auto STAGE = [&](int q, int c) {
        char* base = smem2 + c * 24576;
        if (q < 12) {
            stage_tile(gX + (size_t)q * 128, H_ * 2, (u16*)base, tid);
            stage64(gWl + (size_t)q * 128, H_ * 2, base + 16384, tid);
        } else {
            const int qa = q - 12;
            const int p = qa >> 1, sc = qa & 1;
            const char* Ab = (const char*)adjA + ((size_t)p * B_ + b) * (S_ * S_ * 2) + sc * 128;
            const char* Bb = (const char*)Rel2 + (((size_t)p * B_ + b) * H_ + h0) * (S_ * 2) + sc * 128;
            stage_tile(Ab, S_ * 2, (u16*)base, tid);
            stage64(Bb, S_ * 2, base + 16384, tid);
        }
    };

    const f32x4 zf = {0.f, 0.f, 0.f, 0.f};
    f32x4 acc[4][2];
    #pragma unroll
    for (int i = 0; i < 4; ++i)
        #pragma unroll
        for (int j = 0; j < 2; ++j) acc[i][j] = zf;

    STAGE(0, 0);
    __syncthreads();

    for (int q = 0; q < 28; ++q) {
        const int c = q & 1;
        if (q < 27) STAGE(q + 1, c ^ 1);
        const u16* lA = (const u16*)(smem2 + c * 24576);
        const u16* lB = (const u16*)(smem2 + c * 24576 + 16384);
        #pragma unroll
        for (int kq = 0; kq < 2; ++kq) {
            const int ck = kq * 64 + hi16;
            s16x8 a[4], bb[2];
            #pragma unroll
            for (int i = 0; i < 4; ++i)
                a[i] = read_frag(lA, wm * 64 + i * 16 + l15, ck);
            #pragma unroll
            for (int j = 0; j < 2; ++j)
                bb[j] = read_frag(lB, wn * 32 + j * 16 + l15, ck);
            #pragma unroll
            for (int i = 0; i < 4; ++i)
                #pragma unroll
                for (int j = 0; j < 2; ++j)
                    acc[i][j] = mfma16(a[i], bb[j], acc[i][j]);
        }
        __syncthreads();
    }

    #pragma unroll
    for (int i = 0; i < 4; ++i) {
        const int tl = wm * 64 + i * 16 + ((lane >> 4) << 2);
        #pragma unroll
        for (int j = 0; j < 2; ++j) {
            const int h = h0 + wn * 32 + j * 16 + l15;
            #pragma unroll
            for (int rr = 0; rr < 4; ++rr) {
                const size_t t = (size_t)b * S_ + tl + rr;
                float v = fmaxf(acc[i][j][rr], 0.f);
                if (lastLayer) Out[t * H_ + h] = v;
                else           Xn[t * H_ + h] = f2bf(v);
            }
        }
    }
}

// ---------- launch ----------
extern "C" void kernel_launch(void* const* d_in, const int* in_sizes, int n_in,
                              void* d_out, int out_size, void* d_ws, size_t ws_size,
                              hipStream_t stream) {
    const float* sent   = (const float*)d_in[0];
    const float* adj    = (const float*)d_in[1];
    const float* W_in   = (const float*)d_in[2];
    const float* b_in   = (const float*)d_in[3];
    const float* W_out  = (const float*)d_in[4];
    const float* b_out  = (const float*)d_in[5];
    const float* Wg_in  = (const float*)d_in[6];
    const float* bg_in  = (const float*)d_in[7];
    const float* Wg_out = (const float*)d_in[8];
    const float* bg_out = (const float*)d_in[9];
    const float* W_loop = (const float*)d_in[10];

    char* ws = (char*)d_ws;
    u16* Wg_all = (u16*)(ws);                  // 18,874,368 B
    u16* W_all  = (u16*)(ws + 18874368);       // 18,874,368 B
    u16* Wlb    = (u16*)(ws + 37748736);       //  2,359,296 B
    u16* adjA   = (u16*)(ws + 40108032);       //  4,194,304 B
    u16* X0     = (u16*)(ws + 44302336);       //  3,145,728 B
    u16* X1     = (u16*)(ws + 47448064);       //  3,145,728 B
    u16* Rel2   = (u16*)(ws + 50593792);       // 25,165,824 B  (end 75,759,616)

    prep_weights<<<4608, 256, 0, stream>>>(Wg_in, Wg_out, W_in, W_out, W_loop, sent,
                                           Wg_all, W_all, Wlb, X0);
    prep_adj<<<8192, 256, 0, stream>>>(adj, adjA);

    u16* Xc = X0;
    u16* Xn = X1;
    for (int l = 0; l < L_; ++l) {
        gemm1_kernel<<<256, 512, 0, stream>>>(Xc, Wg_all, W_all,
                                              bg_in, bg_out, b_in, b_out,
                                              l, Rel2);
        gemm2_kernel<<<dim3(12, 16), 256, 0, stream>>>(adjA, Rel2, Xc, Wlb, l,
                                                       Xn, (float*)d_out, l == L_ - 1);
        u16* t = Xc; Xc = Xn; Xn = t;
    }
}